// Round 4
// baseline (219.544 us; speedup 1.0000x reference)
//
#include <hip/hip_runtime.h>

// out[s,b,d] = x[s,b,d] + (2047.5 - s), shape (4096, 4, 2048) fp32.
// Pure streaming, zero reuse: 268 MB compulsory traffic.
//
// Cache-flag ladder COMPLETE (kernel time = metric - 2 poison fills @ ~79.7):
//   NT load + NT store     : 58.2 us (4.6 TB/s)   <- best
//   NT load + plain store  : 60.0 us (4.5 TB/s)
//   plain  + plain         : 65.4 us (4.1 TB/s)
// Model: harness poison fills leave L3 100% dirty poison; ANY allocating
// access (load or store side) evicts dirty poison -> wasted HBM writeback.
// Full NT bypass wins. Flag space exhausted; keep NT/NT.
//
// R4 change: read-burst length. m13 steady-state float4 copy does 6.29
// TB/s on the same r+w mixed pattern, so 4.6 is not the mixed ceiling.
// Structural lever left: 4 -> 8 float4s per thread (8 outstanding NT
// loads, 8 KB read-run per wave before bus turnaround, 32 KB/block,
// 4096 blocks). Predict kernel 58 -> ~50-54, metric ~209-214. If metric
// unchanged (217-219): wave shape irrelevant, post-poison mixed-stream
// ceiling is ~4.6 TB/s -> declare roofline (this version is NT/NT, so
// keeping it is safe either way).
//
// B*D = 8192 floats per s-row = 2048 float4s => s = i4 >> 11.

typedef float fvec4 __attribute__((ext_vector_type(4)));

__global__ __launch_bounds__(256) void rpe_kernel(const fvec4* __restrict__ x,
                                                  fvec4* __restrict__ out) {
    int base = blockIdx.x * 2048 + threadIdx.x;

    fvec4 v[8];
    int idx[8];
    #pragma unroll
    for (int k = 0; k < 8; ++k) {
        idx[k] = base + k * 256;
        v[k] = __builtin_nontemporal_load(&x[idx[k]]);
    }
    #pragma unroll
    for (int k = 0; k < 8; ++k) {
        float bias = 2047.5f - (float)(idx[k] >> 11);
        v[k] += bias;   // ext_vector: scalar broadcast add
        __builtin_nontemporal_store(v[k], &out[idx[k]]);
    }
}

extern "C" void kernel_launch(void* const* d_in, const int* in_sizes, int n_in,
                              void* d_out, int out_size, void* d_ws, size_t ws_size,
                              hipStream_t stream) {
    const fvec4* x = (const fvec4*)d_in[0];
    fvec4* out = (fvec4*)d_out;
    int n4 = in_sizes[0] / 4;                 // 8,388,608, divisible by 2048
    int blocks = n4 / 2048;                   // 4096 blocks x 256 threads x 8 float4
    rpe_kernel<<<blocks, 256, 0, stream>>>(x, out);
}